// Round 8
// baseline (283.147 us; speedup 1.0000x reference)
//
#include <hip/hip_runtime.h>
#include <math.h>

#define NQ 12
#define DEPTH 3
#define FEAT 768
#define NCLS 10
#define NW 8                 // waves per block
#define AMPS 8               // complex amps per thread
#define PI_HALF 1.57079632679489662f

// ---------- lane-swap helpers ----------
#define DPPF(v, ctrl) __int_as_float(__builtin_amdgcn_update_dpp(0, __float_as_int(v), (ctrl), 0xF, 0xF, true))

template<int M>
__device__ __forceinline__ float swx(float v) {
    if constexpr (M == 1) {          // quad_perm [1,0,3,2]
        return DPPF(v, 0xB1);
    } else if constexpr (M == 2) {   // quad_perm [2,3,0,1]
        return DPPF(v, 0x4E);
    } else if constexpr (M == 4) {   // row_half_mirror (xor7) + quad_perm [3,2,1,0] (xor3)
        float t = DPPF(v, 0x141);
        return DPPF(t, 0x1B);
    } else if constexpr (M == 8) {   // row_ror:8 within 16 lanes == xor8
        return DPPF(v, 0x128);
    } else if constexpr (M == 16) {  // ds_swizzle bitmode xor=16
        return __int_as_float(__builtin_amdgcn_ds_swizzle(__float_as_int(v), 0x401F));
    } else {                         // M == 32
        return __shfl_xor(v, 32, 64);
    }
}

__device__ __forceinline__ float allred(float v) {
    v += swx<1>(v); v += swx<2>(v); v += swx<4>(v);
    v += swx<8>(v); v += swx<16>(v); v += swx<32>(v);
    return v;
}

// ---------- state layout ----------
// amp index i (bit11..bit0), wire q <-> bit (11-q).
//   wires 0,1,2 -> wave bits (logical wave lw: wire0=lw&4, wire1=lw&2, wire2=lw&1)
//   wires 3..8  -> lane bits (wire3=lane&32 ... wire8=lane&1)
//   wires 9..11 -> reg bits  (wire9=j&4, wire10=j&2, wire11=j&1)
// Each thread: vr[8], vi[8].

template<int JM>
__device__ __forceinline__ void rot_reg(float (&vr)[AMPS], float (&vi)[AMPS], const float* m) {
    const float m00r = m[0], m00i = m[1], m01r = m[2], m01i = m[3];
    const float m10r = m[4], m10i = m[5], m11r = m[6], m11i = m[7];
    #pragma unroll
    for (int j = 0; j < AMPS; ++j) if (!(j & JM)) {
        const int j1 = j | JM;
        float r0 = vr[j], i0 = vi[j], r1 = vr[j1], i1 = vi[j1];
        vr[j]  = m00r * r0 - m00i * i0 + m01r * r1 - m01i * i1;
        vi[j]  = m00r * i0 + m00i * r0 + m01r * i1 + m01i * r1;
        vr[j1] = m10r * r0 - m10i * i0 + m11r * r1 - m11i * i1;
        vi[j1] = m10r * i0 + m10i * r0 + m11r * i1 + m11i * r1;
    }
}

template<int LM>
__device__ __forceinline__ void rot_lane(float (&vr)[AMPS], float (&vi)[AMPS], const float* m, int lane) {
    const bool b = (lane & LM) != 0;
    const float csr = b ? m[6] : m[0], csi = b ? m[7] : m[1];
    const float cpr = b ? m[4] : m[2], cpi = b ? m[5] : m[3];
    #pragma unroll
    for (int j = 0; j < AMPS; ++j) {
        float pr = swx<LM>(vr[j]), pi = swx<LM>(vi[j]);
        float r = vr[j], i = vi[j];
        vr[j] = csr * r - csi * i + cpr * pr - cpi * pi;
        vi[j] = csr * i + csi * r + cpr * pi + cpi * pr;
    }
}

template<int PW>
__device__ __forceinline__ void rot_wave(float (&vr)[AMPS], float (&vi)[AMPS], const float* m,
                                         float2 (*ex)[AMPS][64], int lw, int lane) {
    const bool b = (lw & PW) != 0;
    const float csr = b ? m[6] : m[0], csi = b ? m[7] : m[1];
    const float cpr = b ? m[4] : m[2], cpi = b ? m[5] : m[3];
    #pragma unroll
    for (int k = 0; k < AMPS; ++k) ex[lw][k][lane] = make_float2(vr[k], vi[k]);
    __syncthreads();
    #pragma unroll
    for (int k = 0; k < AMPS; ++k) {
        float2 p = ex[lw ^ PW][k][lane];
        float r = vr[k], i = vi[k];
        vr[k] = csr * r - csi * i + cpr * p.x - cpi * p.y;
        vi[k] = csr * i + csi * r + cpr * p.y + cpi * p.x;
    }
    __syncthreads();
}

// Cross-wave CNOT exchange pass (reg ctrl -> wave tgt), all fused per layer.
// LAYER 0: CNOT(11,0)                       -> off = (k&1) ? 4 : 0
// LAYER 1: CNOT(10,0)+CNOT(11,1)            -> off = (k&3) << 1
// LAYER 2: CNOT(9,0)+CNOT(10,1)+CNOT(11,2)  -> off = k
template<int LAYER>
__device__ __forceinline__ void exch_cnot(float (&vr)[AMPS], float (&vi)[AMPS],
                                          float2 (*ex)[AMPS][64], int lw, int lane) {
    #pragma unroll
    for (int k = 0; k < AMPS; ++k) ex[lw][k][lane] = make_float2(vr[k], vi[k]);
    __syncthreads();
    #pragma unroll
    for (int k = 0; k < AMPS; ++k) {
        const int so = (LAYER == 0) ? ((k & 1) ? 4 : 0)
                     : (LAYER == 1) ? ((k & 3) << 1)
                                    : k;
        if (so) {
            float2 p = ex[lw ^ so][k][lane];
            vr[k] = p.x; vi[k] = p.y;
        }
    }
    __syncthreads();
}

template<int JC, int JT>
__device__ __forceinline__ void cnot_rr(float (&vr)[AMPS], float (&vi)[AMPS]) {
    #pragma unroll
    for (int j = 0; j < AMPS; ++j) if ((j & JC) && !(j & JT)) {
        const int j1 = j | JT;
        float tr = vr[j]; vr[j] = vr[j1]; vr[j1] = tr;
        float ti = vi[j]; vi[j] = vi[j1]; vi[j1] = ti;
    }
}

template<int LC, int JT>
__device__ __forceinline__ void cnot_lr(float (&vr)[AMPS], float (&vi)[AMPS], int lane) {
    const bool b = (lane & LC) != 0;
    #pragma unroll
    for (int j = 0; j < AMPS; ++j) if (!(j & JT)) {
        const int j1 = j | JT;
        float r0 = vr[j], r1 = vr[j1];
        vr[j] = b ? r1 : r0;  vr[j1] = b ? r0 : r1;
        float i0 = vi[j], i1 = vi[j1];
        vi[j] = b ? i1 : i0;  vi[j1] = b ? i0 : i1;
    }
}

template<int LC, int LT>
__device__ __forceinline__ void cnot_ll(float (&vr)[AMPS], float (&vi)[AMPS], int lane) {
    const bool b = (lane & LC) != 0;
    #pragma unroll
    for (int j = 0; j < AMPS; ++j) {
        float pr = swx<LT>(vr[j]);
        float pi = swx<LT>(vi[j]);
        vr[j] = b ? pr : vr[j];
        vi[j] = b ? pi : vi[j];
    }
}

template<int PC, int LT>
__device__ __forceinline__ void cnot_wl(float (&vr)[AMPS], float (&vi)[AMPS], int lw) {
    if (lw & PC) {                      // wave-uniform branch
        #pragma unroll
        for (int j = 0; j < AMPS; ++j) {
            vr[j] = swx<LT>(vr[j]);
            vi[j] = swx<LT>(vi[j]);
        }
    }
}

// Block = 1 sample, 8 waves x 64 lanes x 8 amps = 4096 amps.
// 16 state VGPRs/thread + ~35 temps fits the compiler's preferred 64-reg
// budget with NO spill (R6/R7: 16-amp version spilled 222 MB at 64 regs).
// LDS 34 KB -> 4 blocks/CU -> 32 waves/CU (CU max).
__global__ __launch_bounds__(512) void qcircuit_w8(
    const float* __restrict__ x,    // [B, 768]
    const float* __restrict__ Wp,   // [12, 768]
    const float* __restrict__ w,    // [3, 12, 3]
    const float* __restrict__ Wo,   // [10, 12]
    const float* __restrict__ bo,   // [10]
    float* __restrict__ out)        // [B, 10]
{
    const int t = threadIdx.x;
    const int wave = t >> 6;
    const int lane = t & 63;
    const int b = blockIdx.x;

    __shared__ float rotm[DEPTH * NQ][8];
    __shared__ float2 ex[NW][AMPS][64];    // 32 KB cross-wave exchange
    __shared__ float red[NW][NQ];
    __shared__ float sh_ac[NQ], sh_as[NQ], zsh[NQ];

    if (t < DEPTH * NQ) {
        float phi = w[t * 3 + 0], th = w[t * 3 + 1], om = w[t * 3 + 2];
        float ct = cosf(0.5f * th), sn = sinf(0.5f * th);
        float a0 = -0.5f * (phi + om);
        float a1 = 0.5f * (phi - om);
        float c0 = cosf(a0), s0 = sinf(a0);
        float c1 = cosf(a1), s1 = sinf(a1);
        rotm[t][0] = c0 * ct;  rotm[t][1] = s0 * ct;    // m00
        rotm[t][2] = -c1 * sn; rotm[t][3] = -s1 * sn;   // m01
        rotm[t][4] = c1 * sn;  rotm[t][5] = -s1 * sn;   // m10
        rotm[t][6] = c0 * ct;  rotm[t][7] = -s0 * ct;   // m11
    }

    // ---------------- projection: acc[q] = x[b,:] . Wp[q,:] ----------------
    float acc[NQ];
    #pragma unroll
    for (int q = 0; q < NQ; ++q) acc[q] = 0.f;
    {
        const float2* x2  = reinterpret_cast<const float2*>(x + (size_t)b * FEAT);
        const float2* Wp2 = reinterpret_cast<const float2*>(Wp);
        if (t < 384) {                  // 384 float2 = 768 floats
            float2 xv = x2[t];
            #pragma unroll
            for (int q = 0; q < NQ; ++q) {
                float2 wv = Wp2[q * 384 + t];
                acc[q] += xv.x * wv.x + xv.y * wv.y;
            }
        }
    }
    #pragma unroll
    for (int q = 0; q < NQ; ++q) acc[q] = allred(acc[q]);
    if (lane == 0) {
        #pragma unroll
        for (int q = 0; q < NQ; ++q) red[wave][q] = acc[q];
    }
    __syncthreads();
    if (t < NQ) {
        float s = 0.f;
        #pragma unroll
        for (int v = 0; v < NW; ++v) s += red[v][t];
        float h = 0.5f * (tanhf(s) * PI_HALF);
        sh_ac[t] = cosf(h);
        sh_as[t] = sinf(h);
    }
    __syncthreads();

    // ---------------- direct product-state init ----------------
    int lw = wave;     // logical wave: wire0=lw&4, wire1=lw&2, wire2=lw&1
    float vr[AMPS], vi[AMPS];
    float L = ((wave & 4) ? sh_as[0] : sh_ac[0]);
    L *= (wave & 2) ? sh_as[1] : sh_ac[1];
    L *= (wave & 1) ? sh_as[2] : sh_ac[2];
    L *= (lane & 32) ? sh_as[3] : sh_ac[3];
    L *= (lane & 16) ? sh_as[4] : sh_ac[4];
    L *= (lane &  8) ? sh_as[5] : sh_ac[5];
    L *= (lane &  4) ? sh_as[6] : sh_ac[6];
    L *= (lane &  2) ? sh_as[7] : sh_ac[7];
    L *= (lane &  1) ? sh_as[8] : sh_ac[8];
    vr[0] = L;
    #pragma unroll
    for (int wbit = 0; wbit < 3; ++wbit) {       // wire = 11-wbit, j-bit = 1<<wbit
        const int bmask = 1 << wbit;
        const float cw = sh_ac[11 - wbit], sw = sh_as[11 - wbit];
        #pragma unroll
        for (int j = 0; j < AMPS; ++j) {
            if (j < bmask) {
                vr[j | bmask] = vr[j] * sw;
                vr[j] = vr[j] * cw;
            }
        }
    }
    #pragma unroll
    for (int j = 0; j < AMPS; ++j) vi[j] = 0.f;

    // ---------------- StronglyEntanglingLayers ----------------
    #pragma unroll 1
    for (int l = 0; l < DEPTH; ++l) {
        const float* mb = &rotm[l * NQ][0];
        rot_wave<4>(vr, vi, mb + 0 * 8, ex, lw, lane);   // wire 0
        rot_wave<2>(vr, vi, mb + 1 * 8, ex, lw, lane);   // wire 1
        rot_wave<1>(vr, vi, mb + 2 * 8, ex, lw, lane);   // wire 2
        rot_lane<32>(vr, vi, mb + 3 * 8, lane);          // wire 3
        rot_lane<16>(vr, vi, mb + 4 * 8, lane);          // wire 4
        rot_lane< 8>(vr, vi, mb + 5 * 8, lane);          // wire 5
        rot_lane< 4>(vr, vi, mb + 6 * 8, lane);          // wire 6
        rot_lane< 2>(vr, vi, mb + 7 * 8, lane);          // wire 7
        rot_lane< 1>(vr, vi, mb + 8 * 8, lane);          // wire 8
        rot_reg < 4>(vr, vi, mb + 9 * 8);                // wire 9
        rot_reg < 2>(vr, vi, mb + 10 * 8);               // wire 10
        rot_reg < 1>(vr, vi, mb + 11 * 8);               // wire 11
        if (l == 0) {          // r = 1: (0,1),(1,2),(2,3),...,(11,0)
            lw ^= (lw & 4) ? 2 : 0;          // (0,1): logical-wave relabel
            lw ^= (lw & 2) ? 1 : 0;          // (1,2): relabel (after (0,1))
            cnot_wl< 1, 32>(vr, vi, lw);     // (2,3)
            cnot_ll<32, 16>(vr, vi, lane);   // (3,4)
            cnot_ll<16,  8>(vr, vi, lane);   // (4,5)
            cnot_ll< 8,  4>(vr, vi, lane);   // (5,6)
            cnot_ll< 4,  2>(vr, vi, lane);   // (6,7)
            cnot_ll< 2,  1>(vr, vi, lane);   // (7,8)
            cnot_lr< 1,  4>(vr, vi, lane);   // (8,9)
            cnot_rr< 4,  2>(vr, vi);         // (9,10)
            cnot_rr< 2,  1>(vr, vi);         // (10,11)
            exch_cnot<0>(vr, vi, ex, lw, lane); // (11,0)
        } else if (l == 1) {   // r = 2
            lw ^= (lw & 4) ? 1 : 0;          // (0,2): relabel
            cnot_wl< 2, 32>(vr, vi, lw);     // (1,3)
            cnot_wl< 1, 16>(vr, vi, lw);     // (2,4)
            cnot_ll<32,  8>(vr, vi, lane);   // (3,5)
            cnot_ll<16,  4>(vr, vi, lane);   // (4,6)
            cnot_ll< 8,  2>(vr, vi, lane);   // (5,7)
            cnot_ll< 4,  1>(vr, vi, lane);   // (6,8)
            cnot_lr< 2,  4>(vr, vi, lane);   // (7,9)
            cnot_lr< 1,  2>(vr, vi, lane);   // (8,10)
            cnot_rr< 4,  1>(vr, vi);         // (9,11)
            exch_cnot<1>(vr, vi, ex, lw, lane); // (10,0)+(11,1)
        } else {               // r = 3
            cnot_wl< 4, 32>(vr, vi, lw);     // (0,3)
            cnot_wl< 2, 16>(vr, vi, lw);     // (1,4)
            cnot_wl< 1,  8>(vr, vi, lw);     // (2,5)
            cnot_ll<32,  4>(vr, vi, lane);   // (3,6)
            cnot_ll<16,  2>(vr, vi, lane);   // (4,7)
            cnot_ll< 8,  1>(vr, vi, lane);   // (5,8)
            cnot_lr< 4,  4>(vr, vi, lane);   // (6,9)
            cnot_lr< 2,  2>(vr, vi, lane);   // (7,10)
            cnot_lr< 1,  1>(vr, vi, lane);   // (8,11)
            exch_cnot<2>(vr, vi, ex, lw, lane); // (9,0)+(10,1)+(11,2)
        }
    }

    // ---------------- PauliZ expectations ----------------
    float ptot = 0.f, zn4 = 0.f, zn2 = 0.f, zn1 = 0.f;
    #pragma unroll
    for (int j = 0; j < AMPS; ++j) {
        float p = vr[j] * vr[j] + vi[j] * vi[j];
        ptot += p;
        if (j & 4) zn4 += p;
        if (j & 2) zn2 += p;
        if (j & 1) zn1 += p;
    }
    float zp[NQ];
    zp[0] = (lw & 4)    ? -ptot : ptot;
    zp[1] = (lw & 2)    ? -ptot : ptot;
    zp[2] = (lw & 1)    ? -ptot : ptot;
    zp[3] = (lane & 32) ? -ptot : ptot;
    zp[4] = (lane & 16) ? -ptot : ptot;
    zp[5] = (lane &  8) ? -ptot : ptot;
    zp[6] = (lane &  4) ? -ptot : ptot;
    zp[7] = (lane &  2) ? -ptot : ptot;
    zp[8] = (lane &  1) ? -ptot : ptot;
    zp[9]  = ptot - 2.f * zn4;
    zp[10] = ptot - 2.f * zn2;
    zp[11] = ptot - 2.f * zn1;
    #pragma unroll
    for (int q = 0; q < NQ; ++q) zp[q] = allred(zp[q]);
    if (lane == 0) {
        #pragma unroll
        for (int q = 0; q < NQ; ++q) red[wave][q] = zp[q];
    }
    __syncthreads();
    if (t < NQ) {
        float s = 0.f;
        #pragma unroll
        for (int v = 0; v < NW; ++v) s += red[v][t];
        zsh[t] = s;
    }
    __syncthreads();

    // ---------------- output head ----------------
    if (t < NCLS) {
        float o = bo[t];
        #pragma unroll
        for (int q = 0; q < NQ; ++q) o = fmaf(zsh[q], Wo[t * NQ + q], o);
        out[(size_t)b * NCLS + t] = o;
    }
}

extern "C" void kernel_launch(void* const* d_in, const int* in_sizes, int n_in,
                              void* d_out, int out_size, void* d_ws, size_t ws_size,
                              hipStream_t stream) {
    const float* x  = (const float*)d_in[0];   // [B,768]
    const float* Wp = (const float*)d_in[1];   // [12,768]
    const float* w  = (const float*)d_in[2];   // [3,12,3]
    const float* Wo = (const float*)d_in[3];   // [10,12]
    const float* bo = (const float*)d_in[4];   // [10]
    float* out = (float*)d_out;

    const int B = in_sizes[0] / FEAT;          // 4096
    qcircuit_w8<<<B, 512, 0, stream>>>(x, Wp, w, Wo, bo, out);
}

// Round 9
// 184.985 us; speedup vs baseline: 1.5306x; 1.5306x over previous
//
#include <hip/hip_runtime.h>
#include <math.h>

#define NQ 12
#define DEPTH 3
#define FEAT 768
#define NCLS 10
#define NW 8                 // waves per block
#define AMPS 8               // complex amps per thread
#define PI_HALF 1.57079632679489662f

typedef float v2f __attribute__((ext_vector_type(2)));

// ---------- packed complex helpers (VOP3P packed fp32) ----------
// d = {A.lo*z.lo, A.hi*z.lo}            (broadcast z.lo via op_sel)
__device__ __forceinline__ v2f pk_mul_bl(v2f A, v2f z) {
    v2f d;
    asm("v_pk_mul_f32 %0, %1, %2 op_sel:[0,0] op_sel_hi:[1,0]"
        : "=v"(d) : "v"(A), "v"(z));
    return d;
}
// d += {A.lo*z.lo, A.hi*z.lo}
__device__ __forceinline__ void pk_fma_bl(v2f& d, v2f A, v2f z) {
    asm("v_pk_fma_f32 %0, %1, %2, %0 op_sel:[0,0,0] op_sel_hi:[1,0,1]"
        : "+v"(d) : "v"(A), "v"(z));
}
// d += {B.lo*z.hi, B.hi*z.hi}           (broadcast z.hi via op_sel)
__device__ __forceinline__ void pk_fma_bh(v2f& d, v2f B, v2f z) {
    asm("v_pk_fma_f32 %0, %1, %2, %0 op_sel:[0,1,0] op_sel_hi:[1,1,1]"
        : "+v"(d) : "v"(B), "v"(z));
}
// z' = S*z + P*p (complex 2x2 row): As={sr,si} Bs={-si,sr} Ap={pr,pi} Bp={-pi,pr}
// z'.r = sr*z.r - si*z.i + pr*p.r - pi*p.i ; z'.i = si*z.r + sr*z.i + pi*p.r + pr*p.i
__device__ __forceinline__ v2f cgate(v2f As, v2f Bs, v2f Ap, v2f Bp, v2f z, v2f p) {
    v2f d = pk_mul_bl(As, z);
    pk_fma_bh(d, Bs, z);
    pk_fma_bl(d, Ap, p);
    pk_fma_bh(d, Bp, p);
    return d;
}

// ---------- lane-swap helpers ----------
#define DPPF(v, ctrl) __int_as_float(__builtin_amdgcn_update_dpp(0, __float_as_int(v), (ctrl), 0xF, 0xF, true))

template<int M>
__device__ __forceinline__ float swx(float v) {
    if constexpr (M == 1) {          // quad_perm [1,0,3,2]
        return DPPF(v, 0xB1);
    } else if constexpr (M == 2) {   // quad_perm [2,3,0,1]
        return DPPF(v, 0x4E);
    } else if constexpr (M == 4) {   // row_half_mirror (xor7) + quad_perm [3,2,1,0] (xor3)
        float t = DPPF(v, 0x141);
        return DPPF(t, 0x1B);
    } else if constexpr (M == 8) {   // row_ror:8 within 16 lanes == xor8
        return DPPF(v, 0x128);
    } else if constexpr (M == 16) {  // ds_swizzle bitmode xor=16
        return __int_as_float(__builtin_amdgcn_ds_swizzle(__float_as_int(v), 0x401F));
    } else {                         // M == 32
        return __shfl_xor(v, 32, 64);
    }
}

template<int M>
__device__ __forceinline__ v2f swx2(v2f z) {
    v2f p;
    p.x = swx<M>(z.x);
    p.y = swx<M>(z.y);
    return p;
}

__device__ __forceinline__ float allred(float v) {
    v += swx<1>(v); v += swx<2>(v); v += swx<4>(v);
    v += swx<8>(v); v += swx<16>(v); v += swx<32>(v);
    return v;
}

// ---------- state layout ----------
// amp index i (bit11..bit0), wire q <-> bit (11-q).
//   wires 0,1,2 -> wave bits (logical wave lw: wire0=lw&4, wire1=lw&2, wire2=lw&1)
//   wires 3..8  -> lane bits (wire3=lane&32 ... wire8=lane&1)
//   wires 9..11 -> reg bits  (wire9=j&4, wire10=j&2, wire11=j&1)
// Each thread: v2f z[8] = {re,im}.
//
// Coefficient layout per gate (v2f mcoef[g][8]):
//   [0..3] = b=0 side: As={m00r,m00i} Bs={-m00i,m00r} Ap={m01r,m01i} Bp={-m01i,m01r}
//   [4..7] = b=1 side: As={m11r,m11i} Bs={-m11i,m11r} Ap={m10r,m10i} Bp={-m10i,m10r}

template<int JM>
__device__ __forceinline__ void rot_reg(v2f (&z)[AMPS], const v2f* m) {
    const v2f A0 = m[0], B0 = m[1], P0 = m[2], Q0 = m[3];
    const v2f A1 = m[4], B1 = m[5], P1 = m[6], Q1 = m[7];
    #pragma unroll
    for (int j = 0; j < AMPS; ++j) if (!(j & JM)) {
        const int j1 = j | JM;
        v2f z0 = z[j], z1 = z[j1];
        z[j]  = cgate(A0, B0, P0, Q0, z0, z1);
        z[j1] = cgate(A1, B1, P1, Q1, z1, z0);
    }
}

template<int LM>
__device__ __forceinline__ void rot_lane(v2f (&z)[AMPS], const v2f* m, int lane) {
    const bool b = (lane & LM) != 0;
    const v2f As = b ? m[4] : m[0], Bs = b ? m[5] : m[1];
    const v2f Ap = b ? m[6] : m[2], Bp = b ? m[7] : m[3];
    #pragma unroll
    for (int j = 0; j < AMPS; ++j) {
        v2f p = swx2<LM>(z[j]);
        z[j] = cgate(As, Bs, Ap, Bp, z[j], p);
    }
}

template<int PW>
__device__ __forceinline__ void rot_wave(v2f (&z)[AMPS], const v2f* m,
                                         v2f (*ex)[AMPS][64], int lw, int lane) {
    const bool b = (lw & PW) != 0;
    const v2f As = b ? m[4] : m[0], Bs = b ? m[5] : m[1];
    const v2f Ap = b ? m[6] : m[2], Bp = b ? m[7] : m[3];
    #pragma unroll
    for (int k = 0; k < AMPS; ++k) ex[lw][k][lane] = z[k];
    __syncthreads();
    #pragma unroll
    for (int k = 0; k < AMPS; ++k) {
        v2f p = ex[lw ^ PW][k][lane];
        z[k] = cgate(As, Bs, Ap, Bp, z[k], p);
    }
    __syncthreads();
}

// Cross-wave CNOT exchange pass (reg ctrl -> wave tgt), all fused per layer.
// LAYER 0: CNOT(11,0)                       -> off = (k&1) ? 4 : 0
// LAYER 1: CNOT(10,0)+CNOT(11,1)            -> off = (k&3) << 1
// LAYER 2: CNOT(9,0)+CNOT(10,1)+CNOT(11,2)  -> off = k
template<int LAYER>
__device__ __forceinline__ void exch_cnot(v2f (&z)[AMPS],
                                          v2f (*ex)[AMPS][64], int lw, int lane) {
    #pragma unroll
    for (int k = 0; k < AMPS; ++k) ex[lw][k][lane] = z[k];
    __syncthreads();
    #pragma unroll
    for (int k = 0; k < AMPS; ++k) {
        const int so = (LAYER == 0) ? ((k & 1) ? 4 : 0)
                     : (LAYER == 1) ? ((k & 3) << 1)
                                    : k;
        if (so) z[k] = ex[lw ^ so][k][lane];
    }
    __syncthreads();
}

template<int JC, int JT>
__device__ __forceinline__ void cnot_rr(v2f (&z)[AMPS]) {
    #pragma unroll
    for (int j = 0; j < AMPS; ++j) if ((j & JC) && !(j & JT)) {
        const int j1 = j | JT;
        v2f t = z[j]; z[j] = z[j1]; z[j1] = t;
    }
}

template<int LC, int JT>
__device__ __forceinline__ void cnot_lr(v2f (&z)[AMPS], int lane) {
    const bool b = (lane & LC) != 0;
    #pragma unroll
    for (int j = 0; j < AMPS; ++j) if (!(j & JT)) {
        const int j1 = j | JT;
        v2f z0 = z[j], z1 = z[j1];
        z[j]  = b ? z1 : z0;
        z[j1] = b ? z0 : z1;
    }
}

template<int LC, int LT>
__device__ __forceinline__ void cnot_ll(v2f (&z)[AMPS], int lane) {
    const bool b = (lane & LC) != 0;
    #pragma unroll
    for (int j = 0; j < AMPS; ++j) {
        v2f p = swx2<LT>(z[j]);
        z[j] = b ? p : z[j];
    }
}

template<int PC, int LT>
__device__ __forceinline__ void cnot_wl(v2f (&z)[AMPS], int lw) {
    if (lw & PC) {                      // wave-uniform branch
        #pragma unroll
        for (int j = 0; j < AMPS; ++j) z[j] = swx2<LT>(z[j]);
    }
}

// Block = 1 sample, 8 waves x 64 lanes x 8 amps = 4096 amps.
// Packed fp32 (v_pk_fma_f32) halves gate-arithmetic instruction count vs R8.
__global__ __launch_bounds__(512) void qcircuit_pk(
    const float* __restrict__ x,    // [B, 768]
    const float* __restrict__ Wp,   // [12, 768]
    const float* __restrict__ w,    // [3, 12, 3]
    const float* __restrict__ Wo,   // [10, 12]
    const float* __restrict__ bo,   // [10]
    float* __restrict__ out)        // [B, 10]
{
    const int t = threadIdx.x;
    const int wave = t >> 6;
    const int lane = t & 63;
    const int b = blockIdx.x;

    __shared__ v2f mcoef[DEPTH * NQ][8];   // 2.3 KB packed gate coefficients
    __shared__ v2f ex[NW][AMPS][64];       // 32 KB cross-wave exchange
    __shared__ float red[NW][NQ];
    __shared__ float sh_ac[NQ], sh_as[NQ], zsh[NQ];

    if (t < DEPTH * NQ) {
        float phi = w[t * 3 + 0], th = w[t * 3 + 1], om = w[t * 3 + 2];
        float ct = cosf(0.5f * th), sn = sinf(0.5f * th);
        float a0 = -0.5f * (phi + om);
        float a1 = 0.5f * (phi - om);
        float c0 = cosf(a0), s0 = sinf(a0);
        float c1 = cosf(a1), s1 = sinf(a1);
        // m00 = {c0*ct, s0*ct}; m01 = {-c1*sn, -s1*sn}; m10 = {c1*sn, -s1*sn}; m11 = {c0*ct, -s0*ct}
        float m00r = c0 * ct,  m00i = s0 * ct;
        float m01r = -c1 * sn, m01i = -s1 * sn;
        float m10r = c1 * sn,  m10i = -s1 * sn;
        float m11r = c0 * ct,  m11i = -s0 * ct;
        mcoef[t][0] = v2f{m00r, m00i};  mcoef[t][1] = v2f{-m00i, m00r};
        mcoef[t][2] = v2f{m01r, m01i};  mcoef[t][3] = v2f{-m01i, m01r};
        mcoef[t][4] = v2f{m11r, m11i};  mcoef[t][5] = v2f{-m11i, m11r};
        mcoef[t][6] = v2f{m10r, m10i};  mcoef[t][7] = v2f{-m10i, m10r};
    }

    // ---------------- projection: acc[q] = x[b,:] . Wp[q,:] ----------------
    float acc[NQ];
    #pragma unroll
    for (int q = 0; q < NQ; ++q) acc[q] = 0.f;
    {
        const float2* x2  = reinterpret_cast<const float2*>(x + (size_t)b * FEAT);
        const float2* Wp2 = reinterpret_cast<const float2*>(Wp);
        if (t < 384) {                  // 384 float2 = 768 floats
            float2 xv = x2[t];
            #pragma unroll
            for (int q = 0; q < NQ; ++q) {
                float2 wv = Wp2[q * 384 + t];
                acc[q] += xv.x * wv.x + xv.y * wv.y;
            }
        }
    }
    #pragma unroll
    for (int q = 0; q < NQ; ++q) acc[q] = allred(acc[q]);
    if (lane == 0) {
        #pragma unroll
        for (int q = 0; q < NQ; ++q) red[wave][q] = acc[q];
    }
    __syncthreads();
    if (t < NQ) {
        float s = 0.f;
        #pragma unroll
        for (int v = 0; v < NW; ++v) s += red[v][t];
        float h = 0.5f * (tanhf(s) * PI_HALF);
        sh_ac[t] = cosf(h);
        sh_as[t] = sinf(h);
    }
    __syncthreads();

    // ---------------- direct product-state init ----------------
    int lw = wave;     // logical wave: wire0=lw&4, wire1=lw&2, wire2=lw&1
    float pr[AMPS];
    float L = ((wave & 4) ? sh_as[0] : sh_ac[0]);
    L *= (wave & 2) ? sh_as[1] : sh_ac[1];
    L *= (wave & 1) ? sh_as[2] : sh_ac[2];
    L *= (lane & 32) ? sh_as[3] : sh_ac[3];
    L *= (lane & 16) ? sh_as[4] : sh_ac[4];
    L *= (lane &  8) ? sh_as[5] : sh_ac[5];
    L *= (lane &  4) ? sh_as[6] : sh_ac[6];
    L *= (lane &  2) ? sh_as[7] : sh_ac[7];
    L *= (lane &  1) ? sh_as[8] : sh_ac[8];
    pr[0] = L;
    #pragma unroll
    for (int wbit = 0; wbit < 3; ++wbit) {       // wire = 11-wbit, j-bit = 1<<wbit
        const int bmask = 1 << wbit;
        const float cw = sh_ac[11 - wbit], sw = sh_as[11 - wbit];
        #pragma unroll
        for (int j = 0; j < AMPS; ++j) {
            if (j < bmask) {
                pr[j | bmask] = pr[j] * sw;
                pr[j] = pr[j] * cw;
            }
        }
    }
    v2f z[AMPS];
    #pragma unroll
    for (int j = 0; j < AMPS; ++j) z[j] = v2f{pr[j], 0.f};

    // ---------------- StronglyEntanglingLayers ----------------
    #pragma unroll 1
    for (int l = 0; l < DEPTH; ++l) {
        const v2f* mb = &mcoef[l * NQ][0];
        rot_wave<4>(z, mb + 0 * 8, ex, lw, lane);   // wire 0
        rot_wave<2>(z, mb + 1 * 8, ex, lw, lane);   // wire 1
        rot_wave<1>(z, mb + 2 * 8, ex, lw, lane);   // wire 2
        rot_lane<32>(z, mb + 3 * 8, lane);          // wire 3
        rot_lane<16>(z, mb + 4 * 8, lane);          // wire 4
        rot_lane< 8>(z, mb + 5 * 8, lane);          // wire 5
        rot_lane< 4>(z, mb + 6 * 8, lane);          // wire 6
        rot_lane< 2>(z, mb + 7 * 8, lane);          // wire 7
        rot_lane< 1>(z, mb + 8 * 8, lane);          // wire 8
        rot_reg < 4>(z, mb + 9 * 8);                // wire 9
        rot_reg < 2>(z, mb + 10 * 8);               // wire 10
        rot_reg < 1>(z, mb + 11 * 8);               // wire 11
        if (l == 0) {          // r = 1: (0,1),(1,2),(2,3),...,(11,0)
            lw ^= (lw & 4) ? 2 : 0;          // (0,1): logical-wave relabel
            lw ^= (lw & 2) ? 1 : 0;          // (1,2): relabel (after (0,1))
            cnot_wl< 1, 32>(z, lw);          // (2,3)
            cnot_ll<32, 16>(z, lane);        // (3,4)
            cnot_ll<16,  8>(z, lane);        // (4,5)
            cnot_ll< 8,  4>(z, lane);        // (5,6)
            cnot_ll< 4,  2>(z, lane);        // (6,7)
            cnot_ll< 2,  1>(z, lane);        // (7,8)
            cnot_lr< 1,  4>(z, lane);        // (8,9)
            cnot_rr< 4,  2>(z);              // (9,10)
            cnot_rr< 2,  1>(z);              // (10,11)
            exch_cnot<0>(z, ex, lw, lane);   // (11,0)
        } else if (l == 1) {   // r = 2
            lw ^= (lw & 4) ? 1 : 0;          // (0,2): relabel
            cnot_wl< 2, 32>(z, lw);          // (1,3)
            cnot_wl< 1, 16>(z, lw);          // (2,4)
            cnot_ll<32,  8>(z, lane);        // (3,5)
            cnot_ll<16,  4>(z, lane);        // (4,6)
            cnot_ll< 8,  2>(z, lane);        // (5,7)
            cnot_ll< 4,  1>(z, lane);        // (6,8)
            cnot_lr< 2,  4>(z, lane);        // (7,9)
            cnot_lr< 1,  2>(z, lane);        // (8,10)
            cnot_rr< 4,  1>(z);              // (9,11)
            exch_cnot<1>(z, ex, lw, lane);   // (10,0)+(11,1)
        } else {               // r = 3
            cnot_wl< 4, 32>(z, lw);          // (0,3)
            cnot_wl< 2, 16>(z, lw);          // (1,4)
            cnot_wl< 1,  8>(z, lw);          // (2,5)
            cnot_ll<32,  4>(z, lane);        // (3,6)
            cnot_ll<16,  2>(z, lane);        // (4,7)
            cnot_ll< 8,  1>(z, lane);        // (5,8)
            cnot_lr< 4,  4>(z, lane);        // (6,9)
            cnot_lr< 2,  2>(z, lane);        // (7,10)
            cnot_lr< 1,  1>(z, lane);        // (8,11)
            exch_cnot<2>(z, ex, lw, lane);   // (9,0)+(10,1)+(11,2)
        }
    }

    // ---------------- PauliZ expectations ----------------
    float ptot = 0.f, zn4 = 0.f, zn2 = 0.f, zn1 = 0.f;
    #pragma unroll
    for (int j = 0; j < AMPS; ++j) {
        float p = z[j].x * z[j].x + z[j].y * z[j].y;
        ptot += p;
        if (j & 4) zn4 += p;
        if (j & 2) zn2 += p;
        if (j & 1) zn1 += p;
    }
    float zp[NQ];
    zp[0] = (lw & 4)    ? -ptot : ptot;
    zp[1] = (lw & 2)    ? -ptot : ptot;
    zp[2] = (lw & 1)    ? -ptot : ptot;
    zp[3] = (lane & 32) ? -ptot : ptot;
    zp[4] = (lane & 16) ? -ptot : ptot;
    zp[5] = (lane &  8) ? -ptot : ptot;
    zp[6] = (lane &  4) ? -ptot : ptot;
    zp[7] = (lane &  2) ? -ptot : ptot;
    zp[8] = (lane &  1) ? -ptot : ptot;
    zp[9]  = ptot - 2.f * zn4;
    zp[10] = ptot - 2.f * zn2;
    zp[11] = ptot - 2.f * zn1;
    #pragma unroll
    for (int q = 0; q < NQ; ++q) zp[q] = allred(zp[q]);
    if (lane == 0) {
        #pragma unroll
        for (int q = 0; q < NQ; ++q) red[wave][q] = zp[q];
    }
    __syncthreads();
    if (t < NQ) {
        float s = 0.f;
        #pragma unroll
        for (int v = 0; v < NW; ++v) s += red[v][t];
        zsh[t] = s;
    }
    __syncthreads();

    // ---------------- output head ----------------
    if (t < NCLS) {
        float o = bo[t];
        #pragma unroll
        for (int q = 0; q < NQ; ++q) o = fmaf(zsh[q], Wo[t * NQ + q], o);
        out[(size_t)b * NCLS + t] = o;
    }
}

extern "C" void kernel_launch(void* const* d_in, const int* in_sizes, int n_in,
                              void* d_out, int out_size, void* d_ws, size_t ws_size,
                              hipStream_t stream) {
    const float* x  = (const float*)d_in[0];   // [B,768]
    const float* Wp = (const float*)d_in[1];   // [12,768]
    const float* w  = (const float*)d_in[2];   // [3,12,3]
    const float* Wo = (const float*)d_in[3];   // [10,12]
    const float* bo = (const float*)d_in[4];   // [10]
    float* out = (float*)d_out;

    const int B = in_sizes[0] / FEAT;          // 4096
    qcircuit_pk<<<B, 512, 0, stream>>>(x, Wp, w, Wo, bo, out);
}